// Round 8
// baseline (211.327 us; speedup 1.0000x reference)
//
#include <hip/hip_runtime.h>
#include <math.h>

// Dims (fixed by the problem)
constexpr int Bb = 2, Nn = 512, Tt = 12, Ee = 128, Hh = 8, Dd = 16;
constexpr int NTOK   = Bb * Nn * Tt;      // 12288 tokens
constexpr int PROJ   = NTOK * Ee;         // 1572864 elems per [B,N,T,E] tensor
constexpr int SLICES = Bb * Hh * Tt;      // 192 attention slices
constexpr int NSL    = Nn * Dd;           // 8192 elems per (slice, qk tensor)
constexpr long SLE   = (long)SLICES * NSL;
constexpr int NSL17  = 17 * 512;          // vt per-slice stride (d=16 -> ones row)
constexpr long SLE17 = (long)SLICES * NSL17;

// Workspace layout (ushorts):
//   qk   : 5 QK-role tensors x {hi,lo} bf16 [s][hl][slice][n][d], PRE-SCALED
//          by sqrt(1/4*log2e); compact s: 0=Qf 1=Kf 2=Qs 3=Ks 4=Qfs
//   vt   : 2 V tensors bf16 transposed [s][slice][d(17)][n]; d=16 row = 1.0
//   wf   : 7 weight mats x {hi,lo} in B-fragment layout (QK weights scaled)
//   ctxh : 4 attention outputs, bf16 HI plane, token-major [ty][B,N,T,E]
//   ctxl : matching bf16 LO (residual) plane

struct PtrPack { const float* x[6]; const float* W[6]; };
struct WPack   { const float* W[7]; };

typedef __attribute__((ext_vector_type(8)))  short bf16x8;
typedef __attribute__((ext_vector_type(16))) float f32x16;
union FragU { bf16x8 v; unsigned u[4]; };

__device__ __forceinline__ unsigned pk_bf16(float a, float b) {
  unsigned r;
  asm("v_cvt_pk_bf16_f32 %0, %1, %2" : "=v"(r) : "v"(a), "v"(b));
  return r;
}
// fp32 -> bf16 hi + bf16 residual-lo fragments (8 elems)
__device__ __forceinline__ void split_frag(const float e[8], bf16x8& hv, bf16x8& lv) {
  FragU H, L;
  #pragma unroll
  for (int i = 0; i < 4; ++i) {
    const unsigned h = pk_bf16(e[2*i], e[2*i+1]);
    const float h0 = __uint_as_float(h << 16);
    const float h1 = __uint_as_float(h & 0xffff0000u);
    L.u[i] = pk_bf16(e[2*i] - h0, e[2*i+1] - h1);
    H.u[i] = h;
  }
  hv = H.v; lv = L.v;
}

// ---------------------------------------------------------------------------
// prep_w: split 7 weight matrices into hi/lo bf16 B-operand fragments.
// QK-role weights (WfQ,WfK,WsQ,WsK) pre-scaled by sqrt(0.25*log2e).
// ---------------------------------------------------------------------------
__global__ __launch_bounds__(256) void prep_w_kernel(
    WPack wp, unsigned short* __restrict__ wf)
{
  const int m = blockIdx.x;
  const float SQ = sqrtf(0.25f * 1.4426950408889634f);
  const float scale = (m == 0 || m == 1 || m == 3 || m == 4) ? SQ : 1.0f;
  const float* __restrict__ W = wp.W[m];
  for (int e = threadIdx.x; e < 2048; e += 256) {
    const int ct = e >> 9, ks = (e >> 6) & 7, lane = e & 63;
    const int ql = lane & 31, hi = lane >> 5;
    const int c = ct * 32 + ql, k0 = ks * 16 + hi * 8;
    float w[8];
    #pragma unroll
    for (int j = 0; j < 8; ++j) w[j] = W[(size_t)(k0 + j) * Ee + c] * scale;
    bf16x8 hv, lv;
    split_frag(w, hv, lv);
    *(bf16x8*)&wf[((size_t)(m * 2 + 0) * 2048 + e) * 8] = hv;
    *(bf16x8*)&wf[((size_t)(m * 2 + 1) * 2048 + e) * 8] = lv;
  }
}

// ---------------------------------------------------------------------------
// proj_mfma (round-7 form, known-good): y = x @ W' via 32x32x16 bf16 MFMA,
// 3-term hi/lo split (4-term for ty==3).  Block = (b, t, n-chunk of 32);
// x tile staged via LDS; epilogue writes attn-ready operands coalesced.
// ---------------------------------------------------------------------------
__global__ __launch_bounds__(256) void proj_mfma_kernel(
    PtrPack pp, const float* __restrict__ Kj, const float* __restrict__ Vfp,
    unsigned short* __restrict__ qk, unsigned short* __restrict__ vt,
    const unsigned short* __restrict__ wf)
{
  __shared__ float XS[32][132];
  const int ty = blockIdx.y;
  const int g  = blockIdx.x;          // (bt<<4) | nc
  const int nc = g & 15;
  const int bt = g >> 4;              // 0..23
  const int b  = bt / Tt, t = bt % Tt;
  const int n0 = nc * 32;
  const int tid = threadIdx.x;
  const int wave = tid >> 6, lane = tid & 63;
  const int ql = lane & 31, hi = lane >> 5;

  const float* __restrict__ xg = pp.x[ty];
  for (int i = tid; i < 1024; i += 256) {
    const int row = i >> 5, ch = i & 31;
    *(float4*)&XS[row][ch * 4] =
        *(const float4*)&xg[((size_t)(b * Nn + n0 + row) * Tt + t) * Ee + ch * 4];
  }
  __syncthreads();

  f32x16 acc;
  #pragma unroll
  for (int r = 0; r < 16; ++r) acc[r] = 0.f;

  const unsigned short* __restrict__ wbase =
      wf + ((size_t)(ty * 2) * 2048 + wave * 512 + lane) * 8;

  for (int ks = 0; ks < 8; ++ks) {
    float e8[8];
    *(float4*)&e8[0] = *(const float4*)&XS[ql][ks * 16 + hi * 8];
    *(float4*)&e8[4] = *(const float4*)&XS[ql][ks * 16 + hi * 8 + 4];
    bf16x8 xh, xl;
    split_frag(e8, xh, xl);
    const bf16x8 wh = *(const bf16x8*)&wbase[(size_t)ks * 512];
    const bf16x8 wl = *(const bf16x8*)&wbase[(size_t)ks * 512 + 2048 * 8];
    acc = __builtin_amdgcn_mfma_f32_32x32x16_bf16(xh, wh, acc, 0, 0, 0);
    acc = __builtin_amdgcn_mfma_f32_32x32x16_bf16(xh, wl, acc, 0, 0, 0);
    acc = __builtin_amdgcn_mfma_f32_32x32x16_bf16(xl, wh, acc, 0, 0, 0);
    if (ty == 3)
      acc = __builtin_amdgcn_mfma_f32_32x32x16_bf16(xl, wl, acc, 0, 0, 0);
  }
  __syncthreads();   // done reading x tile

  #pragma unroll
  for (int r = 0; r < 16; ++r)
    XS[(r & 3) + 8 * (r >> 2) + 4 * hi][wave * 32 + ql] = acc[r];
  __syncthreads();

  if (ty == 2 || ty == 5) {           // V tensors -> transposed [slice][d][n]
    if (tid < 128) {
      const int h = tid >> 4, d = tid & 15;
      const int slice = (b * Hh + h) * Tt + t;
      const long vsel = (ty == 5);
      float v[32];
      #pragma unroll
      for (int n = 0; n < 32; ++n) v[n] = XS[n][h * 16 + d];
      FragU F[4];
      #pragma unroll
      for (int i = 0; i < 16; ++i)
        F[i >> 2].u[i & 3] = pk_bf16(v[2 * i], v[2 * i + 1]);
      unsigned short* __restrict__ dst =
          vt + vsel * SLE17 + (size_t)slice * NSL17 + d * 512 + n0;
      #pragma unroll
      for (int i = 0; i < 4; ++i) *(bf16x8*)&dst[i * 8] = F[i].v;
      if (d == 0) {                   // ones row (d=16) for the l-column trick
        FragU O_;
        #pragma unroll
        for (int i = 0; i < 4; ++i) O_.u[i] = 0x3F803F80u;
        unsigned short* __restrict__ op =
            vt + vsel * SLE17 + (size_t)slice * NSL17 + 16 * 512 + n0;
        #pragma unroll
        for (int i = 0; i < 4; ++i) *(bf16x8*)&op[i * 8] = O_.v;
      }
    }
  } else {                            // QK-role tensors -> hi/lo planes
    const int h = tid >> 5, nn = tid & 31;
    const int slice = (b * Hh + h) * Tt + t;
    const int n = n0 + nn;
    float v[16];
    #pragma unroll
    for (int d = 0; d < 16; ++d) v[d] = XS[nn][h * 16 + d];
    FragU HI[2], LO[2];
    #pragma unroll
    for (int i = 0; i < 8; ++i) {
      const unsigned hw = pk_bf16(v[2 * i], v[2 * i + 1]);
      const float h0 = __uint_as_float(hw << 16);
      const float h1 = __uint_as_float(hw & 0xffff0000u);
      HI[i >> 2].u[i & 3] = hw;
      LO[i >> 2].u[i & 3] = pk_bf16(v[2 * i] - h0, v[2 * i + 1] - h1);
    }
    const int s = (ty == 0) ? 0 : (ty == 1) ? 1 : (ty == 3) ? 2 : 3;
    unsigned short* __restrict__ hp =
        qk + (size_t)(s * 2 + 0) * SLE + (size_t)slice * NSL + n * 16;
    unsigned short* __restrict__ lp =
        qk + (size_t)(s * 2 + 1) * SLE + (size_t)slice * NSL + n * 16;
    *(bf16x8*)&hp[0] = HI[0].v;  *(bf16x8*)&hp[8] = HI[1].v;
    *(bf16x8*)&lp[0] = LO[0].v;  *(bf16x8*)&lp[8] = LO[1].v;
    if (ty == 3) {                    // FlowSpeed: v = Qs*SQ -> Qfs*SQ (s=4)
      const float SQ  = sqrtf(0.25f * 1.4426950408889634f);
      const float RSQ = 1.0f / SQ;
      const float kj = Kj[n];
      const float iv = 1.0f / (Vfp[n] + 1e-5f);
      float gv[16];
      #pragma unroll
      for (int d = 0; d < 16; ++d) {
        const float vq = v[d] * RSQ;
        gv[d] = SQ * (kj * (vq - vq * vq * iv));
      }
      FragU GH[2], GL[2];
      #pragma unroll
      for (int i = 0; i < 8; ++i) {
        const unsigned hw = pk_bf16(gv[2 * i], gv[2 * i + 1]);
        const float h0 = __uint_as_float(hw << 16);
        const float h1 = __uint_as_float(hw & 0xffff0000u);
        GH[i >> 2].u[i & 3] = hw;
        GL[i >> 2].u[i & 3] = pk_bf16(gv[2 * i] - h0, gv[2 * i + 1] - h1);
      }
      unsigned short* __restrict__ gp =
          qk + (size_t)(4 * 2 + 0) * SLE + (size_t)slice * NSL + n * 16;
      unsigned short* __restrict__ glp =
          qk + (size_t)(4 * 2 + 1) * SLE + (size_t)slice * NSL + n * 16;
      *(bf16x8*)&gp[0]  = GH[0].v;  *(bf16x8*)&gp[8]  = GH[1].v;
      *(bf16x8*)&glp[0] = GL[0].v;  *(bf16x8*)&glp[8] = GL[1].v;
    }
  }
}

// ---------------------------------------------------------------------------
// attn: MFMA flash attention.  Block = 256 thr (4 waves) = one (slice,type);
// wave owns 128 q-rows = FOUR independent qt-chains (ILP; K/V loads amortized
// over 2x work vs round 7).  Repack uses v_permlane32_swap_b32: one swap
// yields both pa.u[0] (lo|lo) and pa.u[2] (hi-cross) -- bit-identical to the
// validated shfl_xor+select path, no DS-pipe waits.
// Epilogue: normalize, then store ctx as bf16 hi + residual-lo planes
// (exactly the split out_mfma consumes -- same numerics as round 7).
// ---------------------------------------------------------------------------
__global__ __launch_bounds__(256) void attn_mfma_kernel(
    const unsigned short* __restrict__ qk, const unsigned short* __restrict__ vt,
    unsigned short* __restrict__ ctxh, unsigned short* __restrict__ ctxl)
{
  const int slice = blockIdx.x;
  const int ty    = blockIdx.y;
  const int a_s[4] = {0, 1, 3, 2};   // queries: Qf, Kf, Ks, Qs
  const int b_s[4] = {1, 4, 0, 3};   // keys   : Kf, Qfs, Qf, Ks
  const int v_s[4] = {0, 0, 1, 1};   // values : Vf, Vf, Vs, Vs

  const unsigned short* __restrict__ Ah =
      qk + (size_t)(a_s[ty] * 2 + 0) * SLE + (size_t)slice * NSL;
  const unsigned short* __restrict__ Al =
      qk + (size_t)(a_s[ty] * 2 + 1) * SLE + (size_t)slice * NSL;
  const unsigned short* __restrict__ Kh_ =
      qk + (size_t)(b_s[ty] * 2 + 0) * SLE + (size_t)slice * NSL;
  const unsigned short* __restrict__ Kl_ =
      qk + (size_t)(b_s[ty] * 2 + 1) * SLE + (size_t)slice * NSL;
  const unsigned short* __restrict__ Vt_ =
      vt + (size_t)v_s[ty] * SLE17 + (size_t)slice * NSL17;

  const int tid  = threadIdx.x;
  const int wave = tid >> 6;
  const int lane = tid & 63;
  const int hi   = lane >> 5;
  const int ql   = lane & 31;
  const int q0   = wave * 128;            // 4 qt-tiles of 32 rows each
  const int dv   = (ql < 16) ? ql : 16;   // lanes 16-31 -> ones row (l column)
  const unsigned short* __restrict__ vbase = Vt_ + dv * 512;

  // Q fragments (B-operand): lane(ql,hi) holds Q[q0+qt*32+ql][hi*8+j]
  bf16x8 qh[4], qlo[4];
  #pragma unroll
  for (int qt = 0; qt < 4; ++qt) {
    const int qrow = q0 + qt * 32 + ql;
    qh[qt]  = *(const bf16x8*)&Ah[qrow * 16 + hi * 8];
    qlo[qt] = *(const bf16x8*)&Al[qrow * 16 + hi * 8];
  }

  f32x16 Z;
  #pragma unroll
  for (int r = 0; r < 16; ++r) Z[r] = 0.0f;

  f32x16 o[4];
  float  m_[4] = {-1e30f, -1e30f, -1e30f, -1e30f};
  #pragma unroll
  for (int qt = 0; qt < 4; ++qt)
    #pragma unroll
    for (int r = 0; r < 16; ++r) o[qt][r] = 0.0f;

  for (int kc = 0; kc < Nn; kc += 32) {
    const int krow = kc + ql;
    const bf16x8 kh = *(const bf16x8*)&Kh_[krow * 16 + hi * 8];
    const bf16x8 kl = *(const bf16x8*)&Kl_[krow * 16 + hi * 8];
    const bf16x8 vb0 = *(const bf16x8*)&vbase[kc + hi * 8];
    const bf16x8 vb1 = *(const bf16x8*)&vbase[kc + 16 + hi * 8];

    #pragma unroll
    for (int qt = 0; qt < 4; ++qt) {
      f32x16 S;
      S = __builtin_amdgcn_mfma_f32_32x32x16_bf16(kh, qh[qt],  Z, 0, 0, 0);
      S = __builtin_amdgcn_mfma_f32_32x32x16_bf16(kh, qlo[qt], S, 0, 0, 0);
      S = __builtin_amdgcn_mfma_f32_32x32x16_bf16(kl, qh[qt],  S, 0, 0, 0);
      if (ty == 1)
        S = __builtin_amdgcn_mfma_f32_32x32x16_bf16(kl, qlo[qt], S, 0, 0, 0);

      float p[16];
      if (ty == 1) {
        // deferred-rescale online max: per-query max across both halves
        float smax = S[0];
        #pragma unroll
        for (int r = 1; r < 16; ++r) smax = fmaxf(smax, S[r]);
        float cm = fmaxf(smax, __shfl_xor(smax, 32));
        if (!__all(cm <= m_[qt] + 8.0f)) {
          const float nm = fmaxf(m_[qt], cm);
          const float f  = __builtin_amdgcn_exp2f(m_[qt] - nm);
          #pragma unroll
          for (int r = 0; r < 16; ++r) {
            const int qloc = (r & 3) + 8 * (r >> 2) + 4 * hi;
            o[qt][r] *= __shfl(f, qloc);   // rescales l column too
          }
          m_[qt] = nm;
        }
        #pragma unroll
        for (int r = 0; r < 16; ++r)
          p[r] = __builtin_amdgcn_exp2f(S[r] - m_[qt]);
      } else {
        #pragma unroll
        for (int r = 0; r < 16; ++r)
          p[r] = __builtin_amdgcn_exp2f(S[r]);
      }

      // repack P (rows k, col q=ql) into PV A-fragment (row q=ql, k along j)
      // permlane32_swap(a,c): a' = [a.lo | c.lo] (= hi?swc:wa),
      //                       c' = [a.hi | c.hi] (= hi?wc:swa)
      FragU pa0, pa1;
      {
        unsigned wa = pk_bf16(p[0],  p[1]);
        unsigned wb = pk_bf16(p[2],  p[3]);
        unsigned wc = pk_bf16(p[4],  p[5]);
        unsigned wd = pk_bf16(p[6],  p[7]);
        asm("v_permlane32_swap_b32 %0, %1" : "+v"(wa), "+v"(wc));
        asm("v_permlane32_swap_b32 %0, %1" : "+v"(wb), "+v"(wd));
        pa0.u[0] = wa; pa0.u[1] = wb; pa0.u[2] = wc; pa0.u[3] = wd;
        unsigned we = pk_bf16(p[8],  p[9]);
        unsigned wg = pk_bf16(p[10], p[11]);
        unsigned wi = pk_bf16(p[12], p[13]);
        unsigned wj = pk_bf16(p[14], p[15]);
        asm("v_permlane32_swap_b32 %0, %1" : "+v"(we), "+v"(wi));
        asm("v_permlane32_swap_b32 %0, %1" : "+v"(wg), "+v"(wj));
        pa1.u[0] = we; pa1.u[1] = wg; pa1.u[2] = wi; pa1.u[3] = wj;
      }
      o[qt] = __builtin_amdgcn_mfma_f32_32x32x16_bf16(pa0.v, vb0, o[qt], 0, 0, 0);
      o[qt] = __builtin_amdgcn_mfma_f32_32x32x16_bf16(pa1.v, vb1, o[qt], 0, 0, 0);
    }
  }

  // epilogue: l lives in column 16 (lanes 16/48); normalize, split to bf16
  // hi/lo planes, store (32B runs per half-wave).
  const int b = slice / (Hh * Tt);
  const int h = (slice / Tt) % Hh;
  const int t = slice % Tt;
  unsigned short* __restrict__ ch = ctxh + (size_t)ty * PROJ;
  unsigned short* __restrict__ cl = ctxl + (size_t)ty * PROJ;
  const int lsrc = (lane & 32) | 16;
  #pragma unroll
  for (int qt = 0; qt < 4; ++qt) {
    #pragma unroll
    for (int r = 0; r < 16; ++r) {
      const int qloc = (r & 3) + 8 * (r >> 2) + 4 * hi;
      const float lsum = __shfl(o[qt][r], lsrc);
      if (ql < 16) {
        const int n = q0 + qt * 32 + qloc;
        const float val = o[qt][r] * __builtin_amdgcn_rcpf(lsum);
        const unsigned hv = pk_bf16(val, val);
        const float hf = __uint_as_float(hv << 16);
        const unsigned lv = pk_bf16(val - hf, val - hf);
        const size_t off = (((size_t)b * Nn + n) * Tt + t) * Ee + h * Dd + ql;
        ch[off] = (unsigned short)hv;
        cl[off] = (unsigned short)lv;
      }
    }
  }
}

// ---------------------------------------------------------------------------
// out_mfma: out[ty] = ctx[ty] @ Wout + bout.  ctx arrives pre-split as bf16
// hi/lo planes in exactly the A-fragment layout -> direct bf16x8 global
// loads, 3 MFMA per ks, direct 128B-coalesced stores.  No LDS, no split VALU.
// ---------------------------------------------------------------------------
__global__ __launch_bounds__(256) void out_mfma_kernel(
    const unsigned short* __restrict__ ctxh, const unsigned short* __restrict__ ctxl,
    const unsigned short* __restrict__ wf, const float* __restrict__ bout,
    float* __restrict__ out)
{
  const int ty   = blockIdx.y;
  const int tok0 = blockIdx.x * 32;
  const int wave = threadIdx.x >> 6, lane = threadIdx.x & 63;
  const int ql = lane & 31, hi = lane >> 5;

  f32x16 acc;
  #pragma unroll
  for (int r = 0; r < 16; ++r) acc[r] = 0.f;

  const unsigned short* __restrict__ xh_row =
      ctxh + (size_t)ty * PROJ + (size_t)(tok0 + ql) * Ee;
  const unsigned short* __restrict__ xl_row =
      ctxl + (size_t)ty * PROJ + (size_t)(tok0 + ql) * Ee;
  const unsigned short* __restrict__ wbase =
      wf + ((size_t)(6 * 2) * 2048 + wave * 512 + lane) * 8;

  for (int ks = 0; ks < 8; ++ks) {
    const bf16x8 xh = *(const bf16x8*)&xh_row[ks * 16 + hi * 8];
    const bf16x8 xl = *(const bf16x8*)&xl_row[ks * 16 + hi * 8];
    const bf16x8 wh = *(const bf16x8*)&wbase[(size_t)ks * 512];
    const bf16x8 wl = *(const bf16x8*)&wbase[(size_t)ks * 512 + 2048 * 8];
    acc = __builtin_amdgcn_mfma_f32_32x32x16_bf16(xh, wh, acc, 0, 0, 0);
    acc = __builtin_amdgcn_mfma_f32_32x32x16_bf16(xh, wl, acc, 0, 0, 0);
    acc = __builtin_amdgcn_mfma_f32_32x32x16_bf16(xl, wh, acc, 0, 0, 0);
  }

  const int c = wave * 32 + ql;
  const float bc = bout[c];
  float* __restrict__ dst = out + (size_t)ty * PROJ;
  #pragma unroll
  for (int r = 0; r < 16; ++r) {
    const int tok = tok0 + (r & 3) + 8 * (r >> 2) + 4 * hi;
    dst[(size_t)tok * Ee + c] = acc[r] + bc;
  }
}

// ---------------------------------------------------------------------------
extern "C" void kernel_launch(void* const* d_in, const int* in_sizes, int n_in,
                              void* d_out, int out_size, void* d_ws, size_t ws_size,
                              hipStream_t stream) {
  const float* fq  = (const float*)d_in[0];
  const float* fk  = (const float*)d_in[1];
  const float* fv  = (const float*)d_in[2];
  const float* sq  = (const float*)d_in[3];
  const float* sk  = (const float*)d_in[4];
  const float* sv  = (const float*)d_in[5];
  const float* WfQ = (const float*)d_in[6];
  const float* WfK = (const float*)d_in[7];
  const float* WfV = (const float*)d_in[8];
  const float* WsQ = (const float*)d_in[9];
  const float* WsK = (const float*)d_in[10];
  const float* WsV = (const float*)d_in[11];
  const float* Kj  = (const float*)d_in[12];
  const float* Vfp = (const float*)d_in[13];
  const float* Wout = (const float*)d_in[14];
  const float* bout = (const float*)d_in[15];

  unsigned short* qk   = (unsigned short*)d_ws;        // 10 * SLE
  unsigned short* vt   = qk + (size_t)10 * SLE;        // 2 * SLE17
  unsigned short* wf   = vt + (size_t)2 * SLE17;       // 229376
  unsigned short* ctxh = wf + 229376;                  // 4 * PROJ
  unsigned short* ctxl = ctxh + (size_t)4 * PROJ;      // 4 * PROJ

  PtrPack pp;
  pp.x[0] = fq; pp.x[1] = fk; pp.x[2] = fv;
  pp.x[3] = sq; pp.x[4] = sk; pp.x[5] = sv;
  pp.W[0] = WfQ; pp.W[1] = WfK; pp.W[2] = WfV;
  pp.W[3] = WsQ; pp.W[4] = WsK; pp.W[5] = WsV;
  WPack wp;
  wp.W[0] = WfQ; wp.W[1] = WfK; wp.W[2] = WfV;
  wp.W[3] = WsQ; wp.W[4] = WsK; wp.W[5] = WsV; wp.W[6] = Wout;

  prep_w_kernel<<<7, 256, 0, stream>>>(wp, wf);
  proj_mfma_kernel<<<dim3(384, 6), 256, 0, stream>>>(pp, Kj, Vfp, qk, vt, wf);
  attn_mfma_kernel<<<dim3(SLICES, 4), 256, 0, stream>>>(qk, vt, ctxh, ctxl);
  out_mfma_kernel<<<dim3(NTOK / 32, 4), 256, 0, stream>>>(ctxh, ctxl, wf, bout, (float*)d_out);
}

// Round 9
// 206.084 us; speedup vs baseline: 1.0254x; 1.0254x over previous
//
#include <hip/hip_runtime.h>
#include <math.h>

// Dims (fixed by the problem)
constexpr int Bb = 2, Nn = 512, Tt = 12, Ee = 128, Hh = 8, Dd = 16;
constexpr int NTOK   = Bb * Nn * Tt;      // 12288 tokens
constexpr int PROJ   = NTOK * Ee;         // 1572864 elems per [B,N,T,E] tensor
constexpr int SLICES = Bb * Hh * Tt;      // 192 attention slices
constexpr int NSL    = Nn * Dd;           // 8192 elems per (slice, qk tensor)
constexpr long SLE   = (long)SLICES * NSL;
constexpr int NSL17  = 17 * 512;          // vt per-slice stride (d=16 -> ones row)
constexpr long SLE17 = (long)SLICES * NSL17;

// Workspace layout (ushorts):
//   qk   : 5 QK-role tensors x {hi,lo} bf16 [s][hl][slice][n][d], PRE-SCALED
//          by sqrt(1/4*log2e); compact s: 0=Qf 1=Kf 2=Qs 3=Ks 4=Qfs
//   vt   : 2 V tensors bf16 transposed [s][slice][d(17)][n]; d=16 row = 1.0
//   wf   : 7 weight mats x {hi,lo} in B-fragment layout (QK weights scaled)
//   ctxh : 4 attention outputs, bf16 HI plane, token-major [ty][B,N,T,E]
//   ctxl : matching bf16 LO (residual) plane

struct PtrPack { const float* x[6]; const float* W[6]; };
struct WPack   { const float* W[7]; };

typedef __attribute__((ext_vector_type(8)))  short bf16x8;
typedef __attribute__((ext_vector_type(16))) float f32x16;
union FragU { bf16x8 v; unsigned u[4]; };

__device__ __forceinline__ unsigned pk_bf16(float a, float b) {
  unsigned r;
  asm("v_cvt_pk_bf16_f32 %0, %1, %2" : "=v"(r) : "v"(a), "v"(b));
  return r;
}
// fp32 -> bf16 hi + bf16 residual-lo fragments (8 elems)
__device__ __forceinline__ void split_frag(const float e[8], bf16x8& hv, bf16x8& lv) {
  FragU H, L;
  #pragma unroll
  for (int i = 0; i < 4; ++i) {
    const unsigned h = pk_bf16(e[2*i], e[2*i+1]);
    const float h0 = __uint_as_float(h << 16);
    const float h1 = __uint_as_float(h & 0xffff0000u);
    L.u[i] = pk_bf16(e[2*i] - h0, e[2*i+1] - h1);
    H.u[i] = h;
  }
  hv = H.v; lv = L.v;
}

// ---------------------------------------------------------------------------
// prep_w: split 7 weight matrices into hi/lo bf16 B-operand fragments.
// QK-role weights (WfQ,WfK,WsQ,WsK) pre-scaled by sqrt(0.25*log2e).
// ---------------------------------------------------------------------------
__global__ __launch_bounds__(256) void prep_w_kernel(
    WPack wp, unsigned short* __restrict__ wf)
{
  const int m = blockIdx.x;
  const float SQ = sqrtf(0.25f * 1.4426950408889634f);
  const float scale = (m == 0 || m == 1 || m == 3 || m == 4) ? SQ : 1.0f;
  const float* __restrict__ W = wp.W[m];
  for (int e = threadIdx.x; e < 2048; e += 256) {
    const int ct = e >> 9, ks = (e >> 6) & 7, lane = e & 63;
    const int ql = lane & 31, hi = lane >> 5;
    const int c = ct * 32 + ql, k0 = ks * 16 + hi * 8;
    float w[8];
    #pragma unroll
    for (int j = 0; j < 8; ++j) w[j] = W[(size_t)(k0 + j) * Ee + c] * scale;
    bf16x8 hv, lv;
    split_frag(w, hv, lv);
    *(bf16x8*)&wf[((size_t)(m * 2 + 0) * 2048 + e) * 8] = hv;
    *(bf16x8*)&wf[((size_t)(m * 2 + 1) * 2048 + e) * 8] = lv;
  }
}

// ---------------------------------------------------------------------------
// proj_mfma (known-good): y = x @ W' via 32x32x16 bf16 MFMA, 3-term hi/lo
// split (4-term for ty==3).  Block = (b, t, n-chunk of 32); x tile staged
// via LDS; epilogue writes attn-ready operands coalesced.
// ---------------------------------------------------------------------------
__global__ __launch_bounds__(256) void proj_mfma_kernel(
    PtrPack pp, const float* __restrict__ Kj, const float* __restrict__ Vfp,
    unsigned short* __restrict__ qk, unsigned short* __restrict__ vt,
    const unsigned short* __restrict__ wf)
{
  __shared__ float XS[32][132];
  const int ty = blockIdx.y;
  const int g  = blockIdx.x;          // (bt<<4) | nc
  const int nc = g & 15;
  const int bt = g >> 4;              // 0..23
  const int b  = bt / Tt, t = bt % Tt;
  const int n0 = nc * 32;
  const int tid = threadIdx.x;
  const int wave = tid >> 6, lane = tid & 63;
  const int ql = lane & 31, hi = lane >> 5;

  const float* __restrict__ xg = pp.x[ty];
  for (int i = tid; i < 1024; i += 256) {
    const int row = i >> 5, ch = i & 31;
    *(float4*)&XS[row][ch * 4] =
        *(const float4*)&xg[((size_t)(b * Nn + n0 + row) * Tt + t) * Ee + ch * 4];
  }
  __syncthreads();

  f32x16 acc;
  #pragma unroll
  for (int r = 0; r < 16; ++r) acc[r] = 0.f;

  const unsigned short* __restrict__ wbase =
      wf + ((size_t)(ty * 2) * 2048 + wave * 512 + lane) * 8;

  for (int ks = 0; ks < 8; ++ks) {
    float e8[8];
    *(float4*)&e8[0] = *(const float4*)&XS[ql][ks * 16 + hi * 8];
    *(float4*)&e8[4] = *(const float4*)&XS[ql][ks * 16 + hi * 8 + 4];
    bf16x8 xh, xl;
    split_frag(e8, xh, xl);
    const bf16x8 wh = *(const bf16x8*)&wbase[(size_t)ks * 512];
    const bf16x8 wl = *(const bf16x8*)&wbase[(size_t)ks * 512 + 2048 * 8];
    acc = __builtin_amdgcn_mfma_f32_32x32x16_bf16(xh, wh, acc, 0, 0, 0);
    acc = __builtin_amdgcn_mfma_f32_32x32x16_bf16(xh, wl, acc, 0, 0, 0);
    acc = __builtin_amdgcn_mfma_f32_32x32x16_bf16(xl, wh, acc, 0, 0, 0);
    if (ty == 3)
      acc = __builtin_amdgcn_mfma_f32_32x32x16_bf16(xl, wl, acc, 0, 0, 0);
  }
  __syncthreads();   // done reading x tile

  #pragma unroll
  for (int r = 0; r < 16; ++r)
    XS[(r & 3) + 8 * (r >> 2) + 4 * hi][wave * 32 + ql] = acc[r];
  __syncthreads();

  if (ty == 2 || ty == 5) {           // V tensors -> transposed [slice][d][n]
    if (tid < 128) {
      const int h = tid >> 4, d = tid & 15;
      const int slice = (b * Hh + h) * Tt + t;
      const long vsel = (ty == 5);
      float v[32];
      #pragma unroll
      for (int n = 0; n < 32; ++n) v[n] = XS[n][h * 16 + d];
      FragU F[4];
      #pragma unroll
      for (int i = 0; i < 16; ++i)
        F[i >> 2].u[i & 3] = pk_bf16(v[2 * i], v[2 * i + 1]);
      unsigned short* __restrict__ dst =
          vt + vsel * SLE17 + (size_t)slice * NSL17 + d * 512 + n0;
      #pragma unroll
      for (int i = 0; i < 4; ++i) *(bf16x8*)&dst[i * 8] = F[i].v;
      if (d == 0) {                   // ones row (d=16) for the l-column trick
        FragU O_;
        #pragma unroll
        for (int i = 0; i < 4; ++i) O_.u[i] = 0x3F803F80u;
        unsigned short* __restrict__ op =
            vt + vsel * SLE17 + (size_t)slice * NSL17 + 16 * 512 + n0;
        #pragma unroll
        for (int i = 0; i < 4; ++i) *(bf16x8*)&op[i * 8] = O_.v;
      }
    }
  } else {                            // QK-role tensors -> hi/lo planes
    const int h = tid >> 5, nn = tid & 31;
    const int slice = (b * Hh + h) * Tt + t;
    const int n = n0 + nn;
    float v[16];
    #pragma unroll
    for (int d = 0; d < 16; ++d) v[d] = XS[nn][h * 16 + d];
    FragU HI[2], LO[2];
    #pragma unroll
    for (int i = 0; i < 8; ++i) {
      const unsigned hw = pk_bf16(v[2 * i], v[2 * i + 1]);
      const float h0 = __uint_as_float(hw << 16);
      const float h1 = __uint_as_float(hw & 0xffff0000u);
      HI[i >> 2].u[i & 3] = hw;
      LO[i >> 2].u[i & 3] = pk_bf16(v[2 * i] - h0, v[2 * i + 1] - h1);
    }
    const int s = (ty == 0) ? 0 : (ty == 1) ? 1 : (ty == 3) ? 2 : 3;
    unsigned short* __restrict__ hp =
        qk + (size_t)(s * 2 + 0) * SLE + (size_t)slice * NSL + n * 16;
    unsigned short* __restrict__ lp =
        qk + (size_t)(s * 2 + 1) * SLE + (size_t)slice * NSL + n * 16;
    *(bf16x8*)&hp[0] = HI[0].v;  *(bf16x8*)&hp[8] = HI[1].v;
    *(bf16x8*)&lp[0] = LO[0].v;  *(bf16x8*)&lp[8] = LO[1].v;
    if (ty == 3) {                    // FlowSpeed: v = Qs*SQ -> Qfs*SQ (s=4)
      const float SQ  = sqrtf(0.25f * 1.4426950408889634f);
      const float RSQ = 1.0f / SQ;
      const float kj = Kj[n];
      const float iv = 1.0f / (Vfp[n] + 1e-5f);
      float gv[16];
      #pragma unroll
      for (int d = 0; d < 16; ++d) {
        const float vq = v[d] * RSQ;
        gv[d] = SQ * (kj * (vq - vq * vq * iv));
      }
      FragU GH[2], GL[2];
      #pragma unroll
      for (int i = 0; i < 8; ++i) {
        const unsigned hw = pk_bf16(gv[2 * i], gv[2 * i + 1]);
        const float h0 = __uint_as_float(hw << 16);
        const float h1 = __uint_as_float(hw & 0xffff0000u);
        GH[i >> 2].u[i & 3] = hw;
        GL[i >> 2].u[i & 3] = pk_bf16(gv[2 * i] - h0, gv[2 * i + 1] - h1);
      }
      unsigned short* __restrict__ gp =
          qk + (size_t)(4 * 2 + 0) * SLE + (size_t)slice * NSL + n * 16;
      unsigned short* __restrict__ glp =
          qk + (size_t)(4 * 2 + 1) * SLE + (size_t)slice * NSL + n * 16;
      *(bf16x8*)&gp[0]  = GH[0].v;  *(bf16x8*)&gp[8]  = GH[1].v;
      *(bf16x8*)&glp[0] = GL[0].v;  *(bf16x8*)&glp[8] = GL[1].v;
    }
  }
}

// ---------------------------------------------------------------------------
// attn: MFMA flash attention.  Block = 256 thr (4 waves); grid z splits the
// 512 q-rows into 2 halves -> 1536 blocks (~6/CU), wave owns 64 q-rows =
// 2 qt-chains at VGPR ~56 (round-7 register budget, round-8 permlane repack).
// No LDS, no block syncs: pure wave-level scheduling.
// ---------------------------------------------------------------------------
__global__ __launch_bounds__(256) void attn_mfma_kernel(
    const unsigned short* __restrict__ qk, const unsigned short* __restrict__ vt,
    unsigned short* __restrict__ ctxh, unsigned short* __restrict__ ctxl)
{
  const int slice = blockIdx.x;
  const int ty    = blockIdx.y;
  const int a_s[4] = {0, 1, 3, 2};   // queries: Qf, Kf, Ks, Qs
  const int b_s[4] = {1, 4, 0, 3};   // keys   : Kf, Qfs, Qf, Ks
  const int v_s[4] = {0, 0, 1, 1};   // values : Vf, Vf, Vs, Vs

  const unsigned short* __restrict__ Ah =
      qk + (size_t)(a_s[ty] * 2 + 0) * SLE + (size_t)slice * NSL;
  const unsigned short* __restrict__ Al =
      qk + (size_t)(a_s[ty] * 2 + 1) * SLE + (size_t)slice * NSL;
  const unsigned short* __restrict__ Kh_ =
      qk + (size_t)(b_s[ty] * 2 + 0) * SLE + (size_t)slice * NSL;
  const unsigned short* __restrict__ Kl_ =
      qk + (size_t)(b_s[ty] * 2 + 1) * SLE + (size_t)slice * NSL;
  const unsigned short* __restrict__ Vt_ =
      vt + (size_t)v_s[ty] * SLE17 + (size_t)slice * NSL17;

  const int tid  = threadIdx.x;
  const int wave = tid >> 6;
  const int lane = tid & 63;
  const int hi   = lane >> 5;
  const int ql   = lane & 31;
  const int q0   = blockIdx.z * 256 + wave * 64;   // 2 qt-tiles of 32 rows
  const int dv   = (ql < 16) ? ql : 16;   // lanes 16-31 -> ones row (l column)
  const unsigned short* __restrict__ vbase = Vt_ + dv * 512;

  // Q fragments (B-operand): lane(ql,hi) holds Q[q0+qt*32+ql][hi*8+j]
  bf16x8 qh[2], qlo[2];
  #pragma unroll
  for (int qt = 0; qt < 2; ++qt) {
    const int qrow = q0 + qt * 32 + ql;
    qh[qt]  = *(const bf16x8*)&Ah[qrow * 16 + hi * 8];
    qlo[qt] = *(const bf16x8*)&Al[qrow * 16 + hi * 8];
  }

  f32x16 Z;
  #pragma unroll
  for (int r = 0; r < 16; ++r) Z[r] = 0.0f;

  f32x16 o[2];
  float  m_[2] = {-1e30f, -1e30f};
  #pragma unroll
  for (int qt = 0; qt < 2; ++qt)
    #pragma unroll
    for (int r = 0; r < 16; ++r) o[qt][r] = 0.0f;

  for (int kc = 0; kc < Nn; kc += 32) {
    const int krow = kc + ql;
    const bf16x8 kh = *(const bf16x8*)&Kh_[krow * 16 + hi * 8];
    const bf16x8 kl = *(const bf16x8*)&Kl_[krow * 16 + hi * 8];
    const bf16x8 vb0 = *(const bf16x8*)&vbase[kc + hi * 8];
    const bf16x8 vb1 = *(const bf16x8*)&vbase[kc + 16 + hi * 8];

    #pragma unroll
    for (int qt = 0; qt < 2; ++qt) {
      f32x16 S;
      S = __builtin_amdgcn_mfma_f32_32x32x16_bf16(kh, qh[qt],  Z, 0, 0, 0);
      S = __builtin_amdgcn_mfma_f32_32x32x16_bf16(kh, qlo[qt], S, 0, 0, 0);
      S = __builtin_amdgcn_mfma_f32_32x32x16_bf16(kl, qh[qt],  S, 0, 0, 0);
      if (ty == 1)
        S = __builtin_amdgcn_mfma_f32_32x32x16_bf16(kl, qlo[qt], S, 0, 0, 0);

      float p[16];
      if (ty == 1) {
        // deferred-rescale online max: per-query max across both halves
        float smax = S[0];
        #pragma unroll
        for (int r = 1; r < 16; ++r) smax = fmaxf(smax, S[r]);
        float cm = fmaxf(smax, __shfl_xor(smax, 32));
        if (!__all(cm <= m_[qt] + 8.0f)) {
          const float nm = fmaxf(m_[qt], cm);
          const float f  = __builtin_amdgcn_exp2f(m_[qt] - nm);
          #pragma unroll
          for (int r = 0; r < 16; ++r) {
            const int qloc = (r & 3) + 8 * (r >> 2) + 4 * hi;
            o[qt][r] *= __shfl(f, qloc);   // rescales l column too
          }
          m_[qt] = nm;
        }
        #pragma unroll
        for (int r = 0; r < 16; ++r)
          p[r] = __builtin_amdgcn_exp2f(S[r] - m_[qt]);
      } else {
        #pragma unroll
        for (int r = 0; r < 16; ++r)
          p[r] = __builtin_amdgcn_exp2f(S[r]);
      }

      // repack P (rows k, col q=ql) into PV A-fragment (row q=ql, k along j)
      // permlane32_swap(a,c): a' = [a.lo|c.lo], c' = [a.hi|c.hi]
      // (bit-identical to the validated shfl_xor+select path; round-8 proven)
      FragU pa0, pa1;
      {
        unsigned wa = pk_bf16(p[0],  p[1]);
        unsigned wb = pk_bf16(p[2],  p[3]);
        unsigned wc = pk_bf16(p[4],  p[5]);
        unsigned wd = pk_bf16(p[6],  p[7]);
        asm("v_permlane32_swap_b32 %0, %1" : "+v"(wa), "+v"(wc));
        asm("v_permlane32_swap_b32 %0, %1" : "+v"(wb), "+v"(wd));
        pa0.u[0] = wa; pa0.u[1] = wb; pa0.u[2] = wc; pa0.u[3] = wd;
        unsigned we = pk_bf16(p[8],  p[9]);
        unsigned wg = pk_bf16(p[10], p[11]);
        unsigned wi = pk_bf16(p[12], p[13]);
        unsigned wj = pk_bf16(p[14], p[15]);
        asm("v_permlane32_swap_b32 %0, %1" : "+v"(we), "+v"(wi));
        asm("v_permlane32_swap_b32 %0, %1" : "+v"(wg), "+v"(wj));
        pa1.u[0] = we; pa1.u[1] = wg; pa1.u[2] = wi; pa1.u[3] = wj;
      }
      o[qt] = __builtin_amdgcn_mfma_f32_32x32x16_bf16(pa0.v, vb0, o[qt], 0, 0, 0);
      o[qt] = __builtin_amdgcn_mfma_f32_32x32x16_bf16(pa1.v, vb1, o[qt], 0, 0, 0);
    }
  }

  // epilogue: l lives in column 16 (lanes 16/48); normalize, split to bf16
  // hi/lo planes, store (32B runs per half-wave).
  const int b = slice / (Hh * Tt);
  const int h = (slice / Tt) % Hh;
  const int t = slice % Tt;
  unsigned short* __restrict__ ch = ctxh + (size_t)ty * PROJ;
  unsigned short* __restrict__ cl = ctxl + (size_t)ty * PROJ;
  const int lsrc = (lane & 32) | 16;
  #pragma unroll
  for (int qt = 0; qt < 2; ++qt) {
    #pragma unroll
    for (int r = 0; r < 16; ++r) {
      const int qloc = (r & 3) + 8 * (r >> 2) + 4 * hi;
      const float lsum = __shfl(o[qt][r], lsrc);
      if (ql < 16) {
        const int n = q0 + qt * 32 + qloc;
        const float val = o[qt][r] * __builtin_amdgcn_rcpf(lsum);
        const unsigned hv = pk_bf16(val, val);
        const float hf = __uint_as_float(hv << 16);
        const unsigned lv = pk_bf16(val - hf, val - hf);
        const size_t off = (((size_t)b * Nn + n) * Tt + t) * Ee + h * Dd + ql;
        ch[off] = (unsigned short)hv;
        cl[off] = (unsigned short)lv;
      }
    }
  }
}

// ---------------------------------------------------------------------------
// out_mfma: out[ty] = ctx[ty] @ Wout + bout.  ctx arrives pre-split as bf16
// hi/lo planes in exactly the A-fragment layout -> direct bf16x8 global
// loads, 3 MFMA per ks, direct 128B-coalesced stores.  No LDS, no split VALU.
// ---------------------------------------------------------------------------
__global__ __launch_bounds__(256) void out_mfma_kernel(
    const unsigned short* __restrict__ ctxh, const unsigned short* __restrict__ ctxl,
    const unsigned short* __restrict__ wf, const float* __restrict__ bout,
    float* __restrict__ out)
{
  const int ty   = blockIdx.y;
  const int tok0 = blockIdx.x * 32;
  const int wave = threadIdx.x >> 6, lane = threadIdx.x & 63;
  const int ql = lane & 31, hi = lane >> 5;

  f32x16 acc;
  #pragma unroll
  for (int r = 0; r < 16; ++r) acc[r] = 0.f;

  const unsigned short* __restrict__ xh_row =
      ctxh + (size_t)ty * PROJ + (size_t)(tok0 + ql) * Ee;
  const unsigned short* __restrict__ xl_row =
      ctxl + (size_t)ty * PROJ + (size_t)(tok0 + ql) * Ee;
  const unsigned short* __restrict__ wbase =
      wf + ((size_t)(6 * 2) * 2048 + wave * 512 + lane) * 8;

  for (int ks = 0; ks < 8; ++ks) {
    const bf16x8 xh = *(const bf16x8*)&xh_row[ks * 16 + hi * 8];
    const bf16x8 xl = *(const bf16x8*)&xl_row[ks * 16 + hi * 8];
    const bf16x8 wh = *(const bf16x8*)&wbase[(size_t)ks * 512];
    const bf16x8 wl = *(const bf16x8*)&wbase[(size_t)ks * 512 + 2048 * 8];
    acc = __builtin_amdgcn_mfma_f32_32x32x16_bf16(xh, wh, acc, 0, 0, 0);
    acc = __builtin_amdgcn_mfma_f32_32x32x16_bf16(xh, wl, acc, 0, 0, 0);
    acc = __builtin_amdgcn_mfma_f32_32x32x16_bf16(xl, wh, acc, 0, 0, 0);
  }

  const int c = wave * 32 + ql;
  const float bc = bout[c];
  float* __restrict__ dst = out + (size_t)ty * PROJ;
  #pragma unroll
  for (int r = 0; r < 16; ++r) {
    const int tok = tok0 + (r & 3) + 8 * (r >> 2) + 4 * hi;
    dst[(size_t)tok * Ee + c] = acc[r] + bc;
  }
}

// ---------------------------------------------------------------------------
extern "C" void kernel_launch(void* const* d_in, const int* in_sizes, int n_in,
                              void* d_out, int out_size, void* d_ws, size_t ws_size,
                              hipStream_t stream) {
  const float* fq  = (const float*)d_in[0];
  const float* fk  = (const float*)d_in[1];
  const float* fv  = (const float*)d_in[2];
  const float* sq  = (const float*)d_in[3];
  const float* sk  = (const float*)d_in[4];
  const float* sv  = (const float*)d_in[5];
  const float* WfQ = (const float*)d_in[6];
  const float* WfK = (const float*)d_in[7];
  const float* WfV = (const float*)d_in[8];
  const float* WsQ = (const float*)d_in[9];
  const float* WsK = (const float*)d_in[10];
  const float* WsV = (const float*)d_in[11];
  const float* Kj  = (const float*)d_in[12];
  const float* Vfp = (const float*)d_in[13];
  const float* Wout = (const float*)d_in[14];
  const float* bout = (const float*)d_in[15];

  unsigned short* qk   = (unsigned short*)d_ws;        // 10 * SLE
  unsigned short* vt   = qk + (size_t)10 * SLE;        // 2 * SLE17
  unsigned short* wf   = vt + (size_t)2 * SLE17;       // 229376
  unsigned short* ctxh = wf + 229376;                  // 4 * PROJ
  unsigned short* ctxl = ctxh + (size_t)4 * PROJ;      // 4 * PROJ

  PtrPack pp;
  pp.x[0] = fq; pp.x[1] = fk; pp.x[2] = fv;
  pp.x[3] = sq; pp.x[4] = sk; pp.x[5] = sv;
  pp.W[0] = WfQ; pp.W[1] = WfK; pp.W[2] = WfV;
  pp.W[3] = WsQ; pp.W[4] = WsK; pp.W[5] = WsV;
  WPack wp;
  wp.W[0] = WfQ; wp.W[1] = WfK; wp.W[2] = WfV;
  wp.W[3] = WsQ; wp.W[4] = WsK; wp.W[5] = WsV; wp.W[6] = Wout;

  prep_w_kernel<<<7, 256, 0, stream>>>(wp, wf);
  proj_mfma_kernel<<<dim3(384, 6), 256, 0, stream>>>(pp, Kj, Vfp, qk, vt, wf);
  attn_mfma_kernel<<<dim3(SLICES, 4, 2), 256, 0, stream>>>(qk, vt, ctxh, ctxl);
  out_mfma_kernel<<<dim3(NTOK / 32, 4), 256, 0, stream>>>(ctxh, ctxl, wf, bout, (float*)d_out);
}

// Round 10
// 190.181 us; speedup vs baseline: 1.1112x; 1.0836x over previous
//
#include <hip/hip_runtime.h>
#include <math.h>

// Dims (fixed by the problem)
constexpr int Bb = 2, Nn = 512, Tt = 12, Ee = 128, Hh = 8, Dd = 16;
constexpr int NTOK   = Bb * Nn * Tt;      // 12288 tokens
constexpr int PROJ   = NTOK * Ee;         // 1572864 elems per [B,N,T,E] tensor
constexpr int SLICES = Bb * Hh * Tt;      // 192 attention slices
constexpr int NSL    = Nn * Dd;           // 8192 elems per (slice, qk tensor)
constexpr long SLE   = (long)SLICES * NSL;
constexpr int NSL17  = 17 * 512;          // vt per-slice stride (d=16 -> ones row)
constexpr long SLE17 = (long)SLICES * NSL17;

// Workspace layout (ushorts):
//   qk : 5 QK-role tensors x {hi,lo} bf16 [s][hl][slice][n][d], PRE-SCALED
//        by sqrt(1/4*log2e); compact s: 0=Qf 1=Kf 2=Qs 3=Ks 4=Qfs
//   vt : 2 V tensors bf16 transposed [s][slice][d(17)][n]; d=16 row = 1.0
//   wf : 7 weight mats x {hi,lo} in B-fragment layout (QK weights scaled)

struct PtrPack { const float* x[6]; const float* W[6]; };
struct WPack   { const float* W[7]; };

typedef __attribute__((ext_vector_type(8)))  short bf16x8;
typedef __attribute__((ext_vector_type(16))) float f32x16;
union FragU { bf16x8 v; unsigned u[4]; };

__device__ __forceinline__ unsigned pk_bf16(float a, float b) {
  unsigned r;
  asm("v_cvt_pk_bf16_f32 %0, %1, %2" : "=v"(r) : "v"(a), "v"(b));
  return r;
}
// fp32 -> bf16 hi + bf16 residual-lo fragments (8 elems)
__device__ __forceinline__ void split_frag(const float e[8], bf16x8& hv, bf16x8& lv) {
  FragU H, L;
  #pragma unroll
  for (int i = 0; i < 4; ++i) {
    const unsigned h = pk_bf16(e[2*i], e[2*i+1]);
    const float h0 = __uint_as_float(h << 16);
    const float h1 = __uint_as_float(h & 0xffff0000u);
    L.u[i] = pk_bf16(e[2*i] - h0, e[2*i+1] - h1);
    H.u[i] = h;
  }
  hv = H.v; lv = L.v;
}

// ---------------------------------------------------------------------------
// prep_w: split 7 weight matrices into hi/lo bf16 B-operand fragments.
// QK-role weights (WfQ,WfK,WsQ,WsK) pre-scaled by sqrt(0.25*log2e).
// ---------------------------------------------------------------------------
__global__ __launch_bounds__(256) void prep_w_kernel(
    WPack wp, unsigned short* __restrict__ wf)
{
  const int m = blockIdx.x;
  const float SQ = sqrtf(0.25f * 1.4426950408889634f);
  const float scale = (m == 0 || m == 1 || m == 3 || m == 4) ? SQ : 1.0f;
  const float* __restrict__ W = wp.W[m];
  for (int e = threadIdx.x; e < 2048; e += 256) {
    const int ct = e >> 9, ks = (e >> 6) & 7, lane = e & 63;
    const int ql = lane & 31, hi = lane >> 5;
    const int c = ct * 32 + ql, k0 = ks * 16 + hi * 8;
    float w[8];
    #pragma unroll
    for (int j = 0; j < 8; ++j) w[j] = W[(size_t)(k0 + j) * Ee + c] * scale;
    bf16x8 hv, lv;
    split_frag(w, hv, lv);
    *(bf16x8*)&wf[((size_t)(m * 2 + 0) * 2048 + e) * 8] = hv;
    *(bf16x8*)&wf[((size_t)(m * 2 + 1) * 2048 + e) * 8] = lv;
  }
}

// ---------------------------------------------------------------------------
// proj_mfma (known-good): y = x @ W' via 32x32x16 bf16 MFMA, 3-term hi/lo
// split (4-term for ty==3).  Block = (b, t, n-chunk of 32); x tile staged
// via LDS; epilogue writes attn-ready operands coalesced.
// ---------------------------------------------------------------------------
__global__ __launch_bounds__(256) void proj_mfma_kernel(
    PtrPack pp, const float* __restrict__ Kj, const float* __restrict__ Vfp,
    unsigned short* __restrict__ qk, unsigned short* __restrict__ vt,
    const unsigned short* __restrict__ wf)
{
  __shared__ float XS[32][132];
  const int ty = blockIdx.y;
  const int g  = blockIdx.x;          // (bt<<4) | nc
  const int nc = g & 15;
  const int bt = g >> 4;              // 0..23
  const int b  = bt / Tt, t = bt % Tt;
  const int n0 = nc * 32;
  const int tid = threadIdx.x;
  const int wave = tid >> 6, lane = tid & 63;
  const int ql = lane & 31, hi = lane >> 5;

  const float* __restrict__ xg = pp.x[ty];
  for (int i = tid; i < 1024; i += 256) {
    const int row = i >> 5, ch = i & 31;
    *(float4*)&XS[row][ch * 4] =
        *(const float4*)&xg[((size_t)(b * Nn + n0 + row) * Tt + t) * Ee + ch * 4];
  }
  __syncthreads();

  f32x16 acc;
  #pragma unroll
  for (int r = 0; r < 16; ++r) acc[r] = 0.f;

  const unsigned short* __restrict__ wbase =
      wf + ((size_t)(ty * 2) * 2048 + wave * 512 + lane) * 8;

  for (int ks = 0; ks < 8; ++ks) {
    float e8[8];
    *(float4*)&e8[0] = *(const float4*)&XS[ql][ks * 16 + hi * 8];
    *(float4*)&e8[4] = *(const float4*)&XS[ql][ks * 16 + hi * 8 + 4];
    bf16x8 xh, xl;
    split_frag(e8, xh, xl);
    const bf16x8 wh = *(const bf16x8*)&wbase[(size_t)ks * 512];
    const bf16x8 wl = *(const bf16x8*)&wbase[(size_t)ks * 512 + 2048 * 8];
    acc = __builtin_amdgcn_mfma_f32_32x32x16_bf16(xh, wh, acc, 0, 0, 0);
    acc = __builtin_amdgcn_mfma_f32_32x32x16_bf16(xh, wl, acc, 0, 0, 0);
    acc = __builtin_amdgcn_mfma_f32_32x32x16_bf16(xl, wh, acc, 0, 0, 0);
    if (ty == 3)
      acc = __builtin_amdgcn_mfma_f32_32x32x16_bf16(xl, wl, acc, 0, 0, 0);
  }
  __syncthreads();   // done reading x tile

  #pragma unroll
  for (int r = 0; r < 16; ++r)
    XS[(r & 3) + 8 * (r >> 2) + 4 * hi][wave * 32 + ql] = acc[r];
  __syncthreads();

  if (ty == 2 || ty == 5) {           // V tensors -> transposed [slice][d][n]
    if (tid < 128) {
      const int h = tid >> 4, d = tid & 15;
      const int slice = (b * Hh + h) * Tt + t;
      const long vsel = (ty == 5);
      float v[32];
      #pragma unroll
      for (int n = 0; n < 32; ++n) v[n] = XS[n][h * 16 + d];
      FragU F[4];
      #pragma unroll
      for (int i = 0; i < 16; ++i)
        F[i >> 2].u[i & 3] = pk_bf16(v[2 * i], v[2 * i + 1]);
      unsigned short* __restrict__ dst =
          vt + vsel * SLE17 + (size_t)slice * NSL17 + d * 512 + n0;
      #pragma unroll
      for (int i = 0; i < 4; ++i) *(bf16x8*)&dst[i * 8] = F[i].v;
      if (d == 0) {                   // ones row (d=16) for the l-column trick
        FragU O_;
        #pragma unroll
        for (int i = 0; i < 4; ++i) O_.u[i] = 0x3F803F80u;
        unsigned short* __restrict__ op =
            vt + vsel * SLE17 + (size_t)slice * NSL17 + 16 * 512 + n0;
        #pragma unroll
        for (int i = 0; i < 4; ++i) *(bf16x8*)&op[i * 8] = O_.v;
      }
    }
  } else {                            // QK-role tensors -> hi/lo planes
    const int h = tid >> 5, nn = tid & 31;
    const int slice = (b * Hh + h) * Tt + t;
    const int n = n0 + nn;
    float v[16];
    #pragma unroll
    for (int d = 0; d < 16; ++d) v[d] = XS[nn][h * 16 + d];
    FragU HI[2], LO[2];
    #pragma unroll
    for (int i = 0; i < 8; ++i) {
      const unsigned hw = pk_bf16(v[2 * i], v[2 * i + 1]);
      const float h0 = __uint_as_float(hw << 16);
      const float h1 = __uint_as_float(hw & 0xffff0000u);
      HI[i >> 2].u[i & 3] = hw;
      LO[i >> 2].u[i & 3] = pk_bf16(v[2 * i] - h0, v[2 * i + 1] - h1);
    }
    const int s = (ty == 0) ? 0 : (ty == 1) ? 1 : (ty == 3) ? 2 : 3;
    unsigned short* __restrict__ hp =
        qk + (size_t)(s * 2 + 0) * SLE + (size_t)slice * NSL + n * 16;
    unsigned short* __restrict__ lp =
        qk + (size_t)(s * 2 + 1) * SLE + (size_t)slice * NSL + n * 16;
    *(bf16x8*)&hp[0] = HI[0].v;  *(bf16x8*)&hp[8] = HI[1].v;
    *(bf16x8*)&lp[0] = LO[0].v;  *(bf16x8*)&lp[8] = LO[1].v;
    if (ty == 3) {                    // FlowSpeed: v = Qs*SQ -> Qfs*SQ (s=4)
      const float SQ  = sqrtf(0.25f * 1.4426950408889634f);
      const float RSQ = 1.0f / SQ;
      const float kj = Kj[n];
      const float iv = 1.0f / (Vfp[n] + 1e-5f);
      float gv[16];
      #pragma unroll
      for (int d = 0; d < 16; ++d) {
        const float vq = v[d] * RSQ;
        gv[d] = SQ * (kj * (vq - vq * vq * iv));
      }
      FragU GH[2], GL[2];
      #pragma unroll
      for (int i = 0; i < 8; ++i) {
        const unsigned hw = pk_bf16(gv[2 * i], gv[2 * i + 1]);
        const float h0 = __uint_as_float(hw << 16);
        const float h1 = __uint_as_float(hw & 0xffff0000u);
        GH[i >> 2].u[i & 3] = hw;
        GL[i >> 2].u[i & 3] = pk_bf16(gv[2 * i] - h0, gv[2 * i + 1] - h1);
      }
      unsigned short* __restrict__ gp =
          qk + (size_t)(4 * 2 + 0) * SLE + (size_t)slice * NSL + n * 16;
      unsigned short* __restrict__ glp =
          qk + (size_t)(4 * 2 + 1) * SLE + (size_t)slice * NSL + n * 16;
      *(bf16x8*)&gp[0]  = GH[0].v;  *(bf16x8*)&gp[8]  = GH[1].v;
      *(bf16x8*)&glp[0] = GL[0].v;  *(bf16x8*)&glp[8] = GL[1].v;
    }
  }
}

// ---------------------------------------------------------------------------
// attn_out: FUSED flash attention + output projection.
// Block = 512 thr (8 waves) = one (b, t, ty, 64-token chunk); wave = head h.
// Flash per wave: 2 qt-chains over 512 keys (round-7-validated structure,
// permlane repack, l-column via ones-row).  Normalized ctx (bf16 hi) goes to
// LDS [64][136] (272B rows: 16B-aligned, ~conflict-free), then each wave
// computes one 32x32 tile of ctx @ Wout (2-term hi/lo) + bias -> d_out.
// Eliminates the separate out kernel and all ctx HBM traffic.
// ---------------------------------------------------------------------------
__global__ __launch_bounds__(512) void attn_out_kernel(
    const unsigned short* __restrict__ qk, const unsigned short* __restrict__ vt,
    const unsigned short* __restrict__ wf, const float* __restrict__ bout,
    float* __restrict__ out)
{
  __shared__ unsigned short XH[64][136];   // ctx tile, bf16 hi, padded rows
  const int bt = blockIdx.x;               // 0..23
  const int b  = bt / Tt, t = bt % Tt;
  const int ty = blockIdx.y;
  const int q0 = blockIdx.z * 64;          // token chunk

  const int a_s[4] = {0, 1, 3, 2};   // queries: Qf, Kf, Ks, Qs
  const int b_s[4] = {1, 4, 0, 3};   // keys   : Kf, Qfs, Qf, Ks
  const int v_s[4] = {0, 0, 1, 1};   // values : Vf, Vf, Vs, Vs

  const int tid  = threadIdx.x;
  const int wave = tid >> 6;               // = head h
  const int lane = tid & 63;
  const int hi   = lane >> 5;
  const int ql   = lane & 31;
  const int h    = wave;
  const int slice = (b * Hh + h) * Tt + t;

  const unsigned short* __restrict__ Ah =
      qk + (size_t)(a_s[ty] * 2 + 0) * SLE + (size_t)slice * NSL;
  const unsigned short* __restrict__ Al =
      qk + (size_t)(a_s[ty] * 2 + 1) * SLE + (size_t)slice * NSL;
  const unsigned short* __restrict__ Kh_ =
      qk + (size_t)(b_s[ty] * 2 + 0) * SLE + (size_t)slice * NSL;
  const unsigned short* __restrict__ Kl_ =
      qk + (size_t)(b_s[ty] * 2 + 1) * SLE + (size_t)slice * NSL;
  const unsigned short* __restrict__ Vt_ =
      vt + (size_t)v_s[ty] * SLE17 + (size_t)slice * NSL17;

  const int dv = (ql < 16) ? ql : 16;      // lanes 16-31 -> ones row (l col)
  const unsigned short* __restrict__ vbase = Vt_ + dv * 512;

  // Q fragments (B-operand): lane(ql,hi) holds Q[q0+qt*32+ql][hi*8+j]
  bf16x8 qh[2], qlo[2];
  #pragma unroll
  for (int qt = 0; qt < 2; ++qt) {
    const int qrow = q0 + qt * 32 + ql;
    qh[qt]  = *(const bf16x8*)&Ah[qrow * 16 + hi * 8];
    qlo[qt] = *(const bf16x8*)&Al[qrow * 16 + hi * 8];
  }

  f32x16 Z;
  #pragma unroll
  for (int r = 0; r < 16; ++r) Z[r] = 0.0f;

  f32x16 o[2];
  float  m_[2] = {-1e30f, -1e30f};
  #pragma unroll
  for (int qt = 0; qt < 2; ++qt)
    #pragma unroll
    for (int r = 0; r < 16; ++r) o[qt][r] = 0.0f;

  for (int kc = 0; kc < Nn; kc += 32) {
    const int krow = kc + ql;
    const bf16x8 kh = *(const bf16x8*)&Kh_[krow * 16 + hi * 8];
    const bf16x8 kl = *(const bf16x8*)&Kl_[krow * 16 + hi * 8];
    const bf16x8 vb0 = *(const bf16x8*)&vbase[kc + hi * 8];
    const bf16x8 vb1 = *(const bf16x8*)&vbase[kc + 16 + hi * 8];

    #pragma unroll
    for (int qt = 0; qt < 2; ++qt) {
      f32x16 S;
      S = __builtin_amdgcn_mfma_f32_32x32x16_bf16(kh, qh[qt],  Z, 0, 0, 0);
      S = __builtin_amdgcn_mfma_f32_32x32x16_bf16(kh, qlo[qt], S, 0, 0, 0);
      S = __builtin_amdgcn_mfma_f32_32x32x16_bf16(kl, qh[qt],  S, 0, 0, 0);
      if (ty == 1)
        S = __builtin_amdgcn_mfma_f32_32x32x16_bf16(kl, qlo[qt], S, 0, 0, 0);

      float p[16];
      if (ty == 1) {
        // deferred-rescale online max: per-query max across both halves
        float smax = S[0];
        #pragma unroll
        for (int r = 1; r < 16; ++r) smax = fmaxf(smax, S[r]);
        float cm = fmaxf(smax, __shfl_xor(smax, 32));
        if (!__all(cm <= m_[qt] + 8.0f)) {
          const float nm = fmaxf(m_[qt], cm);
          const float f  = __builtin_amdgcn_exp2f(m_[qt] - nm);
          #pragma unroll
          for (int r = 0; r < 16; ++r) {
            const int qloc = (r & 3) + 8 * (r >> 2) + 4 * hi;
            o[qt][r] *= __shfl(f, qloc);   // rescales l column too
          }
          m_[qt] = nm;
        }
        #pragma unroll
        for (int r = 0; r < 16; ++r)
          p[r] = __builtin_amdgcn_exp2f(S[r] - m_[qt]);
      } else {
        #pragma unroll
        for (int r = 0; r < 16; ++r)
          p[r] = __builtin_amdgcn_exp2f(S[r]);
      }

      // repack P (rows k, col q=ql) into PV A-fragment (row q=ql, k along j)
      // permlane32_swap(a,c): a' = [a.lo|c.lo], c' = [a.hi|c.hi]  (validated)
      FragU pa0, pa1;
      {
        unsigned wa = pk_bf16(p[0],  p[1]);
        unsigned wb = pk_bf16(p[2],  p[3]);
        unsigned wc = pk_bf16(p[4],  p[5]);
        unsigned wd = pk_bf16(p[6],  p[7]);
        asm("v_permlane32_swap_b32 %0, %1" : "+v"(wa), "+v"(wc));
        asm("v_permlane32_swap_b32 %0, %1" : "+v"(wb), "+v"(wd));
        pa0.u[0] = wa; pa0.u[1] = wb; pa0.u[2] = wc; pa0.u[3] = wd;
        unsigned we = pk_bf16(p[8],  p[9]);
        unsigned wg = pk_bf16(p[10], p[11]);
        unsigned wi = pk_bf16(p[12], p[13]);
        unsigned wj = pk_bf16(p[14], p[15]);
        asm("v_permlane32_swap_b32 %0, %1" : "+v"(we), "+v"(wi));
        asm("v_permlane32_swap_b32 %0, %1" : "+v"(wg), "+v"(wj));
        pa1.u[0] = we; pa1.u[1] = wg; pa1.u[2] = wi; pa1.u[3] = wj;
      }
      o[qt] = __builtin_amdgcn_mfma_f32_32x32x16_bf16(pa0.v, vb0, o[qt], 0, 0, 0);
      o[qt] = __builtin_amdgcn_mfma_f32_32x32x16_bf16(pa1.v, vb1, o[qt], 0, 0, 0);
    }
  }

  // flash epilogue: normalize, write bf16 ctx into LDS tile
  const int lsrc = (lane & 32) | 16;
  #pragma unroll
  for (int qt = 0; qt < 2; ++qt) {
    #pragma unroll
    for (int r = 0; r < 16; ++r) {
      const int qloc = (r & 3) + 8 * (r >> 2) + 4 * hi;
      const float lsum = __shfl(o[qt][r], lsrc);
      if (ql < 16) {
        const float val = o[qt][r] * __builtin_amdgcn_rcpf(lsum);
        XH[qt * 32 + qloc][h * 16 + ql] =
            (unsigned short)(pk_bf16(val, val) & 0xffffu);
      }
    }
  }
  __syncthreads();

  // out projection: wave (tt = wave>>2, ct = wave&3) computes tokens
  // [q0+tt*32, +32) x cols [ct*32, +32).  A = ctx-hi from LDS; B = Wout
  // hi/lo fragments (2-term).
  const int tt = wave >> 2, ct = wave & 3;
  f32x16 acc;
  #pragma unroll
  for (int r = 0; r < 16; ++r) acc[r] = 0.f;

  const unsigned short* __restrict__ wbase =
      wf + ((size_t)(6 * 2) * 2048 + ct * 512 + lane) * 8;

  for (int ks = 0; ks < 8; ++ks) {
    const bf16x8 xh = *(const bf16x8*)&XH[tt * 32 + ql][ks * 16 + hi * 8];
    const bf16x8 wh = *(const bf16x8*)&wbase[(size_t)ks * 512];
    const bf16x8 wl = *(const bf16x8*)&wbase[(size_t)ks * 512 + 2048 * 8];
    acc = __builtin_amdgcn_mfma_f32_32x32x16_bf16(xh, wh, acc, 0, 0, 0);
    acc = __builtin_amdgcn_mfma_f32_32x32x16_bf16(xh, wl, acc, 0, 0, 0);
  }

  const int c = ct * 32 + ql;
  const float bc = bout[c];
  float* __restrict__ dst = out + (size_t)ty * PROJ;
  #pragma unroll
  for (int r = 0; r < 16; ++r) {
    const int n = q0 + tt * 32 + (r & 3) + 8 * (r >> 2) + 4 * hi;
    const size_t tok = ((size_t)b * Nn + n) * Tt + t;
    dst[tok * Ee + c] = acc[r] + bc;
  }
}

// ---------------------------------------------------------------------------
extern "C" void kernel_launch(void* const* d_in, const int* in_sizes, int n_in,
                              void* d_out, int out_size, void* d_ws, size_t ws_size,
                              hipStream_t stream) {
  const float* fq  = (const float*)d_in[0];
  const float* fk  = (const float*)d_in[1];
  const float* fv  = (const float*)d_in[2];
  const float* sq  = (const float*)d_in[3];
  const float* sk  = (const float*)d_in[4];
  const float* sv  = (const float*)d_in[5];
  const float* WfQ = (const float*)d_in[6];
  const float* WfK = (const float*)d_in[7];
  const float* WfV = (const float*)d_in[8];
  const float* WsQ = (const float*)d_in[9];
  const float* WsK = (const float*)d_in[10];
  const float* WsV = (const float*)d_in[11];
  const float* Kj  = (const float*)d_in[12];
  const float* Vfp = (const float*)d_in[13];
  const float* Wout = (const float*)d_in[14];
  const float* bout = (const float*)d_in[15];

  unsigned short* qk = (unsigned short*)d_ws;          // 10 * SLE
  unsigned short* vt = qk + (size_t)10 * SLE;          // 2 * SLE17
  unsigned short* wf = vt + (size_t)2 * SLE17;         // 229376

  PtrPack pp;
  pp.x[0] = fq; pp.x[1] = fk; pp.x[2] = fv;
  pp.x[3] = sq; pp.x[4] = sk; pp.x[5] = sv;
  pp.W[0] = WfQ; pp.W[1] = WfK; pp.W[2] = WfV;
  pp.W[3] = WsQ; pp.W[4] = WsK; pp.W[5] = WsV;
  WPack wp;
  wp.W[0] = WfQ; wp.W[1] = WfK; wp.W[2] = WfV;
  wp.W[3] = WsQ; wp.W[4] = WsK; wp.W[5] = WsV; wp.W[6] = Wout;

  prep_w_kernel<<<7, 256, 0, stream>>>(wp, wf);
  proj_mfma_kernel<<<dim3(384, 6), 256, 0, stream>>>(pp, Kj, Vfp, qk, vt, wf);
  attn_out_kernel<<<dim3(24, 4, 8), 512, 0, stream>>>(qk, vt, wf, bout, (float*)d_out);
}